// Round 14
// baseline (772.187 us; speedup 1.0000x reference)
//
#include <hip/hip_runtime.h>
#include <hip/hip_cooperative_groups.h>
#include <math.h>

namespace cg = cooperative_groups;

#define IN_DIM 128
#define HID 64
#define NEG_SLOPE 0.2f
#define LN_EPS 1e-5f
#define ECAP 512            // LDS edge-weight capacity per attn block-iteration (4 dsts)

typedef short bf16x8 __attribute__((ext_vector_type(8)));
typedef float f32x4  __attribute__((ext_vector_type(4)));

// ---------- bf16 helpers ----------
__device__ inline unsigned short f2bf(float f) {
    unsigned u = __float_as_uint(f);
    u += 0x7fffu + ((u >> 16) & 1u);     // round-to-nearest-even
    return (unsigned short)(u >> 16);
}
__device__ inline float bf2f(unsigned short s) {
    return __uint_as_float(((unsigned)s) << 16);
}
__device__ inline float leaky(float v) { return v > 0.0f ? v : NEG_SLOPE * v; }

// ================= single cooperative mega-kernel =================
// Phases (separated by grid.sync()):
//  A init: zero hist, dtype detect (block 0), pack Wt_post/Wt_xw, fold w_s/w_d
//  B hist | C scan1 | D scan partials+apply | E scatter + MFMA x@W_gcn
//  F gcn gather | G attn (edge-parallel weights in LDS + aggregation) | H post MFMA+LN
__global__ __launch_bounds__(256, 4) void k_mega(
    const unsigned long long* ei64, int E, int n, int nscan,
    int* flag, int* hist, int* tmp, int* partial,
    int* row_ptr, int* cursor, int* col,
    const float* x, const float* bgcn,
    const float* Wg, const float* att_s, const float* att_d,
    const float* Wp, const float* Wgcn,
    const float* bp, const float* bg,
    const float* gamma, const float* beta,
    unsigned short* Wt_post, unsigned short* Wt_xw,
    float* w_s, float* w_d, float* dinv,
    unsigned short* xws, unsigned short* h1b,
    float4* a_s, float4* a_d,
    unsigned short* X, float* out)
{
    cg::grid_group gridg = cg::this_grid();
    __shared__ __align__(16) unsigned char smem[40960];
    int t = threadIdx.x;
    int gtid = blockIdx.x * 256 + t;
    int gstride = gridDim.x * 256;

    // ---------------- Phase A ----------------
    for (int i = gtid; i < n; i += gstride) hist[i] = 0;
    for (int p = gtid; p < 2560 + 1024 + 256; p += gstride) {
        if (p < 2560) {
            int c = p & 63, kg = p >> 6;
            bf16x8 v;
#pragma unroll
            for (int j = 0; j < 8; j++) {
                int k = kg * 8 + j;
                float f;
                if (k < 256) f = 0.25f * Wg[(size_t)(k & 63) * 256 + (k >> 6) * 64 + c];
                else         f = Wp[(size_t)(k - 256) * 64 + c];
                v[j] = (short)f2bf(f);
            }
            *(bf16x8*)(&Wt_post[(size_t)p * 8]) = v;
        } else if (p < 3584) {
            int q = p - 2560;
            int c = q & 63, kg = q >> 6;
            bf16x8 v;
#pragma unroll
            for (int j = 0; j < 8; j++)
                v[j] = (short)f2bf(Wgcn[(size_t)(kg * 8 + j) * 64 + c]);
            *(bf16x8*)(&Wt_xw[(size_t)q * 8]) = v;
        } else {
            int q = p - 3584;
            int h = q >> 6, k = q & 63;
            float ss = 0.0f, sd = 0.0f;
            for (int c = 0; c < HID; c++) {
                float w = Wg[(size_t)k * 256 + h * HID + c];
                ss += w * att_s[h * HID + c];
                sd += w * att_d[h * HID + c];
            }
            w_s[h * HID + k] = ss;
            w_d[h * HID + k] = sd;
        }
    }
    if (blockIdx.x == 0) {
        int* s_bad = (int*)smem;
        if (t == 0) *s_bad = 0;
        __syncthreads();
        int lim = E < 4096 ? E : 4096;
        int bad = 0;
        for (int k = t; k < lim; k += 256)
            if (ei64[k] >= (unsigned long long)n) bad = 1;
        if (bad) *s_bad = 1;     // benign race
        __syncthreads();
        if (t == 0) *flag = (*s_bad) ? 0 : 1;   // 1 = genuine int64
    }
    gridg.sync();

    int is64 = *flag;
    const long long* e64 = (const long long*)ei64;
    const int* e32 = (const int*)ei64;

    // ---------------- Phase B: dst histogram ----------------
    for (int i = gtid; i < E; i += gstride) {
        int d = is64 ? (int)e64[E + i] : e32[E + i];
        atomicAdd(&hist[d], 1);
    }
    gridg.sync();

    // ---------------- Phase C: per-chunk scan ----------------
    {
        int* s = (int*)smem;
        for (int cb = blockIdx.x; cb < nscan; cb += gridDim.x) {
            int i = cb * 256 + t;
            int v = (i < n) ? hist[i] : 0;
            s[t] = v;
            __syncthreads();
            for (int off = 1; off < 256; off <<= 1) {
                int xv = (t >= off) ? s[t - off] : 0;
                __syncthreads();
                s[t] += xv;
                __syncthreads();
            }
            tmp[i] = s[t] - v;
            if (t == 255) partial[cb] = s[255];
            __syncthreads();
        }
    }
    gridg.sync();

    // ---------------- Phase D: scan partials (local) + apply ----------------
    {
        int* s = (int*)smem;
        int v = (t < nscan) ? partial[t] : 0;
        s[t] = v;
        __syncthreads();
        for (int off = 1; off < 256; off <<= 1) {
            int xv = (t >= off) ? s[t - off] : 0;
            __syncthreads();
            s[t] += xv;
            __syncthreads();
        }
        for (int cb = blockIdx.x; cb < nscan; cb += gridDim.x) {
            int excl = (cb == 0) ? 0 : s[cb - 1];
            int i = cb * 256 + t;
            if (i < n) {
                int v2 = tmp[i] + excl;
                row_ptr[i] = v2;
                cursor[i] = v2;
                dinv[i] = rsqrtf((float)(hist[i] + 1));   // +1 self-loop
            }
        }
        __syncthreads();
    }
    gridg.sync();

    // ---------------- Phase E: CSR scatter + MFMA x@W_gcn ----------------
    for (int i = gtid; i < E; i += gstride) {
        int sn = is64 ? (int)e64[i] : e32[i];
        int d = is64 ? (int)e64[E + i] : e32[E + i];
        int pos = atomicAdd(&cursor[d], 1);
        col[pos] = sn;
    }
    {
        unsigned short* Wt = (unsigned short*)smem;   // 16 KB
        for (int idx = t; idx < 1024; idx += 256)
            *(bf16x8*)(&Wt[idx * 8]) = *(const bf16x8*)(&Wt_xw[(size_t)idx * 8]);
        __syncthreads();
        int lane = t & 63, li = lane & 15, quad = lane >> 4, wv = t >> 6;
        int ntile = (n + 63) / 64;
        for (int tile = blockIdx.x; tile < ntile; tile += gridDim.x) {
            int r0 = tile * 64 + wv * 16;
            int rload = r0 + li; if (rload > n - 1) rload = n - 1;
            f32x4 acc[4];
#pragma unroll
            for (int i = 0; i < 4; i++) acc[i] = (f32x4){0.f, 0.f, 0.f, 0.f};
            const float* xp = x + (size_t)rload * IN_DIM + quad * 8;
#pragma unroll
            for (int ks = 0; ks < 4; ks++) {
                float4 p0 = *(const float4*)(xp + ks * 32);
                float4 p1 = *(const float4*)(xp + ks * 32 + 4);
                bf16x8 a;
                a[0] = (short)f2bf(p0.x); a[1] = (short)f2bf(p0.y);
                a[2] = (short)f2bf(p0.z); a[3] = (short)f2bf(p0.w);
                a[4] = (short)f2bf(p1.x); a[5] = (short)f2bf(p1.y);
                a[6] = (short)f2bf(p1.z); a[7] = (short)f2bf(p1.w);
                int kg = ks * 4 + quad;
#pragma unroll
                for (int tt = 0; tt < 4; tt++) {
                    bf16x8 bfr = *(const bf16x8*)(&Wt[((kg * 64) + tt * 16 + li) * 8]);
                    acc[tt] = __builtin_amdgcn_mfma_f32_16x16x32_bf16(a, bfr, acc[tt], 0, 0, 0);
                }
            }
#pragma unroll
            for (int reg = 0; reg < 4; reg++) {
                int r = r0 + quad * 4 + reg;
                if (r >= n) continue;
                float dv = dinv[r];
#pragma unroll
                for (int tt = 0; tt < 4; tt++)
                    xws[(size_t)r * HID + tt * 16 + li] = f2bf(acc[tt][reg] * dv);
            }
        }
    }
    gridg.sync();

    // ---------------- Phase F: GCN gather + bias/relu + logit dots ----------------
    {
        int c = t & 63, wv = t >> 6;
        int ndb = (n + 3) / 4;
        for (int db = blockIdx.x; db < ndb; db += gridDim.x) {
            int d = db * 4 + wv;
            if (d < n) {
                int start = row_ptr[d], cnt = hist[d];
                float acc = bf2f(xws[(size_t)d * HID + c]);   // self term
                int k = 0;
                for (; k + 3 < cnt; k += 4) {
                    int s0 = col[start + k],     s1 = col[start + k + 1];
                    int s2 = col[start + k + 2], s3 = col[start + k + 3];
                    float v0 = bf2f(xws[(size_t)s0 * HID + c]);
                    float v1 = bf2f(xws[(size_t)s1 * HID + c]);
                    float v2 = bf2f(xws[(size_t)s2 * HID + c]);
                    float v3 = bf2f(xws[(size_t)s3 * HID + c]);
                    acc += (v0 + v1) + (v2 + v3);
                }
                for (; k < cnt; k++) acc += bf2f(xws[(size_t)col[start + k] * HID + c]);
                float h1c = fmaxf(acc * dinv[d] + bgcn[c], 0.0f);
                h1b[(size_t)d * HID + c] = f2bf(h1c);
                float vs0 = h1c * w_s[c],       vs1 = h1c * w_s[64 + c];
                float vs2 = h1c * w_s[128 + c], vs3 = h1c * w_s[192 + c];
                float vd0 = h1c * w_d[c],       vd1 = h1c * w_d[64 + c];
                float vd2 = h1c * w_d[128 + c], vd3 = h1c * w_d[192 + c];
                for (int o = 32; o > 0; o >>= 1) {
                    vs0 += __shfl_xor(vs0, o, 64); vs1 += __shfl_xor(vs1, o, 64);
                    vs2 += __shfl_xor(vs2, o, 64); vs3 += __shfl_xor(vs3, o, 64);
                    vd0 += __shfl_xor(vd0, o, 64); vd1 += __shfl_xor(vd1, o, 64);
                    vd2 += __shfl_xor(vd2, o, 64); vd3 += __shfl_xor(vd3, o, 64);
                }
                if (c == 0) {
                    a_s[d] = make_float4(vs0, vs1, vs2, vs3);
                    a_d[d] = make_float4(vd0, vd1, vd2, vd3);
                }
            }
        }
    }
    gridg.sync();

    // ---------------- Phase G: attention (edge weights in LDS + aggregation) ----------------
    {
        float4* wls = (float4*)smem;                 // [0, 8192)
        int*    sls = (int*)(smem + 8192);           // [8192, 10240)
        int*    sb  = (int*)(smem + 10240);          // 5 ints
        float4* sad = (float4*)(smem + 10272);       // 4 float4
        int ndb = (n + 3) / 4;
        for (int db = blockIdx.x; db < ndb; db += gridDim.x) {
            int d0 = db * 4;
            if (t == 0) {
                int bptr = row_ptr[d0];
                sb[0] = bptr;
                for (int j = 0; j < 4; j++) {
                    int d = d0 + j;
                    bptr += (d < n) ? hist[d] : 0;
                    sb[j + 1] = bptr;
                }
            }
            if (t < 4 && d0 + t < n) sad[t] = a_d[d0 + t];
            __syncthreads();
            int start0 = sb[0];
            int totc = sb[4] - start0;
            int rel1 = sb[1] - start0, rel2 = sb[2] - start0, rel3 = sb[3] - start0;
            bool fast = (totc <= ECAP);
            if (fast) {
                for (int e = t; e < totc; e += 256) {
                    int s = col[start0 + e];
                    int j = (e >= rel1) + (e >= rel2) + (e >= rel3);
                    float4 as = a_s[s], ad = sad[j];
                    float4 wv4;
                    wv4.x = __expf(leaky(as.x + ad.x));
                    wv4.y = __expf(leaky(as.y + ad.y));
                    wv4.z = __expf(leaky(as.z + ad.z));
                    wv4.w = __expf(leaky(as.w + ad.w));
                    wls[e] = wv4;
                    sls[e] = s;
                }
            }
            __syncthreads();
            int c = t & 63, wv = t >> 6;
            int d = d0 + wv;
            if (d < n) {
                float4 ad = sad[wv];
                float4 asd = a_s[d];
                float w0 = __expf(leaky(asd.x + ad.x));
                float w1 = __expf(leaky(asd.y + ad.y));
                float w2 = __expf(leaky(asd.z + ad.z));
                float w3 = __expf(leaky(asd.w + ad.w));
                float hs = bf2f(h1b[(size_t)d * HID + c]);
                float A0 = w0 * hs, A1 = w1 * hs, A2 = w2 * hs, A3 = w3 * hs;
                float l0 = w0, l1 = w1, l2 = w2, l3 = w3;
                int lo = sb[wv] - start0, hi = sb[wv + 1] - start0;
                if (fast) {
                    int k = lo;
                    for (; k + 3 < hi; k += 4) {
                        int s0 = sls[k], s1 = sls[k + 1], s2 = sls[k + 2], s3 = sls[k + 3];
                        float4 e0 = wls[k], e1 = wls[k + 1], e2 = wls[k + 2], e3 = wls[k + 3];
                        float hv0 = bf2f(h1b[(size_t)s0 * HID + c]);
                        float hv1 = bf2f(h1b[(size_t)s1 * HID + c]);
                        float hv2 = bf2f(h1b[(size_t)s2 * HID + c]);
                        float hv3 = bf2f(h1b[(size_t)s3 * HID + c]);
                        A0 += e0.x * hv0 + e1.x * hv1 + e2.x * hv2 + e3.x * hv3;
                        A1 += e0.y * hv0 + e1.y * hv1 + e2.y * hv2 + e3.y * hv3;
                        A2 += e0.z * hv0 + e1.z * hv1 + e2.z * hv2 + e3.z * hv3;
                        A3 += e0.w * hv0 + e1.w * hv1 + e2.w * hv2 + e3.w * hv3;
                        l0 += (e0.x + e1.x) + (e2.x + e3.x);
                        l1 += (e0.y + e1.y) + (e2.y + e3.y);
                        l2 += (e0.z + e1.z) + (e2.z + e3.z);
                        l3 += (e0.w + e1.w) + (e2.w + e3.w);
                    }
                    for (; k < hi; k++) {
                        int s0 = sls[k];
                        float4 e0 = wls[k];
                        float hv0 = bf2f(h1b[(size_t)s0 * HID + c]);
                        A0 += e0.x * hv0; l0 += e0.x;
                        A1 += e0.y * hv0; l1 += e0.y;
                        A2 += e0.z * hv0; l2 += e0.z;
                        A3 += e0.w * hv0; l3 += e0.w;
                    }
                } else {
                    for (int k = lo; k < hi; k++) {
                        int s0 = col[start0 + k];
                        float4 as = a_s[s0];
                        float u0 = __expf(leaky(as.x + ad.x));
                        float u1 = __expf(leaky(as.y + ad.y));
                        float u2 = __expf(leaky(as.z + ad.z));
                        float u3 = __expf(leaky(as.w + ad.w));
                        float hv0 = bf2f(h1b[(size_t)s0 * HID + c]);
                        A0 += u0 * hv0; l0 += u0;
                        A1 += u1 * hv0; l1 += u1;
                        A2 += u2 * hv0; l2 += u2;
                        A3 += u3 * hv0; l3 += u3;
                    }
                }
                size_t base = (size_t)d * 256;
                X[base + c]       = f2bf(A0 / l0);
                X[base + 64 + c]  = f2bf(A1 / l1);
                X[base + 128 + c] = f2bf(A2 / l2);
                X[base + 192 + c] = f2bf(A3 / l3);
            }
            __syncthreads();
        }
    }
    gridg.sync();

    // ---------------- Phase H: post MFMA GEMM + relu/residual/LN ----------------
    {
        unsigned short* Wt = (unsigned short*)smem;   // 40 KB
        for (int idx = t; idx < 2560; idx += 256)
            *(bf16x8*)(&Wt[idx * 8]) = *(const bf16x8*)(&Wt_post[(size_t)idx * 8]);
        __syncthreads();
        int lane = t & 63, li = lane & 15, quad = lane >> 4, wv = t >> 6;
        int ntile = (n + 127) / 128;
        for (int tile = blockIdx.x; tile < ntile; tile += gridDim.x) {
            int rbase = tile * 128 + wv * 32;
            f32x4 acc_a[2][4], acc_h[2][4];
#pragma unroll
            for (int rt = 0; rt < 2; rt++)
#pragma unroll
                for (int i = 0; i < 4; i++) {
                    acc_a[rt][i] = (f32x4){0.f, 0.f, 0.f, 0.f};
                    acc_h[rt][i] = (f32x4){0.f, 0.f, 0.f, 0.f};
                }
#pragma unroll
            for (int ks = 0; ks < 10; ks++) {
                int kg = ks * 4 + quad;
                bf16x8 b0 = *(const bf16x8*)(&Wt[((kg * 64) + 0 * 16 + li) * 8]);
                bf16x8 b1 = *(const bf16x8*)(&Wt[((kg * 64) + 1 * 16 + li) * 8]);
                bf16x8 b2 = *(const bf16x8*)(&Wt[((kg * 64) + 2 * 16 + li) * 8]);
                bf16x8 b3 = *(const bf16x8*)(&Wt[((kg * 64) + 3 * 16 + li) * 8]);
#pragma unroll
                for (int rt = 0; rt < 2; rt++) {
                    int row = rbase + rt * 16 + li;
                    bf16x8 a;
                    if (ks < 8)
                        a = *(const bf16x8*)(X + (size_t)row * 256 + quad * 8 + ks * 32);
                    else
                        a = *(const bf16x8*)(h1b + (size_t)row * HID + quad * 8 + (ks - 8) * 32);
                    if (ks < 8) {
                        acc_a[rt][0] = __builtin_amdgcn_mfma_f32_16x16x32_bf16(a, b0, acc_a[rt][0], 0, 0, 0);
                        acc_a[rt][1] = __builtin_amdgcn_mfma_f32_16x16x32_bf16(a, b1, acc_a[rt][1], 0, 0, 0);
                        acc_a[rt][2] = __builtin_amdgcn_mfma_f32_16x16x32_bf16(a, b2, acc_a[rt][2], 0, 0, 0);
                        acc_a[rt][3] = __builtin_amdgcn_mfma_f32_16x16x32_bf16(a, b3, acc_a[rt][3], 0, 0, 0);
                    } else {
                        acc_h[rt][0] = __builtin_amdgcn_mfma_f32_16x16x32_bf16(a, b0, acc_h[rt][0], 0, 0, 0);
                        acc_h[rt][1] = __builtin_amdgcn_mfma_f32_16x16x32_bf16(a, b1, acc_h[rt][1], 0, 0, 0);
                        acc_h[rt][2] = __builtin_amdgcn_mfma_f32_16x16x32_bf16(a, b2, acc_h[rt][2], 0, 0, 0);
                        acc_h[rt][3] = __builtin_amdgcn_mfma_f32_16x16x32_bf16(a, b3, acc_h[rt][3], 0, 0, 0);
                    }
                }
            }
#pragma unroll
            for (int rt = 0; rt < 2; rt++) {
#pragma unroll
                for (int reg = 0; reg < 4; reg++) {
                    int r = rbase + rt * 16 + quad * 4 + reg;
                    bool ok = (r < n);
                    float hv[4];
                    float s1 = 0.0f, s2 = 0.0f;
#pragma unroll
                    for (int tt = 0; tt < 4; tt++) {
                        int c = tt * 16 + li;
                        float h1c = ok ? bf2f(h1b[(size_t)r * HID + c]) : 0.0f;
                        float h2 = fmaxf(acc_a[rt][tt][reg] + bg[c], 0.0f);
                        float h = h1c + h2 + acc_h[rt][tt][reg] + bp[c];
                        hv[tt] = h;
                        s1 += h; s2 += h * h;
                    }
                    for (int o = 8; o > 0; o >>= 1) {
                        s1 += __shfl_xor(s1, o, 64);
                        s2 += __shfl_xor(s2, o, 64);
                    }
                    float mu = s1 * (1.0f / 64.0f);
                    float var = s2 * (1.0f / 64.0f) - mu * mu;
                    float rs = rsqrtf(var + LN_EPS);
                    if (ok) {
#pragma unroll
                        for (int tt = 0; tt < 4; tt++) {
                            int c = tt * 16 + li;
                            out[(size_t)r * HID + c] = (hv[tt] - mu) * rs * gamma[c] + beta[c];
                        }
                    }
                }
            }
        }
    }
}

extern "C" void kernel_launch(void* const* d_in, const int* in_sizes, int n_in,
                              void* d_out, int out_size, void* d_ws, size_t ws_size,
                              hipStream_t stream) {
    int n = in_sizes[0] / IN_DIM;
    int E = in_sizes[1] / 2;

    const float* x     = (const float*)d_in[0];
    const void*  ei    = d_in[1];
    const float* W_gcn = (const float*)d_in[2];
    const float* b_gcn = (const float*)d_in[3];
    const float* W_gat = (const float*)d_in[4];
    const float* att_s = (const float*)d_in[5];
    const float* att_d = (const float*)d_in[6];
    const float* b_gat = (const float*)d_in[7];
    const float* W_p   = (const float*)d_in[8];
    const float* b_p   = (const float*)d_in[9];
    const float* gamma = (const float*)d_in[10];
    const float* beta  = (const float*)d_in[11];

    int n_pad  = ((n + 255) / 256) * 256;
    int nscan  = n_pad / 256;                 // must be <= 256
    int n128   = ((n + 127) / 128) * 128;     // row padding for post tiles

    float* ws = (float*)d_ws;
    size_t off = 0;
    int*   flag    = (int*)(ws + off);  off += 4;
    int*   hist    = (int*)(ws + off);  off += n;
    int*   row_ptr = (int*)(ws + off);  off += n;
    int*   cursor  = (int*)(ws + off);  off += n;
    int*   tmp     = (int*)(ws + off);  off += n_pad;
    int*   partial = (int*)(ws + off);  off += 256;
    int*   colv    = (int*)(ws + off);  off += E;
    float* dinv    = ws + off;          off += n;
    float* w_s     = ws + off;          off += 4 * HID;
    float* w_d     = ws + off;          off += 4 * HID;
    off = (off + 3) & ~(size_t)3;
    unsigned short* Wt_post = (unsigned short*)(ws + off); off += 2560 * 8 / 2;
    unsigned short* Wt_xw   = (unsigned short*)(ws + off); off += 1024 * 8 / 2;
    unsigned short* xws = (unsigned short*)(ws + off); off += (size_t)n * HID / 2;
    off = (off + 3) & ~(size_t)3;
    unsigned short* h1b = (unsigned short*)(ws + off); off += (size_t)n128 * HID / 2;
    off = (off + 3) & ~(size_t)3;
    float4* a_sv   = (float4*)(ws + off); off += (size_t)n * 4;
    float4* a_dv   = (float4*)(ws + off); off += (size_t)n * 4;
    off = (off + 3) & ~(size_t)3;
    unsigned short* X = (unsigned short*)(ws + off); off += (size_t)n128 * 256 / 2;

    // co-resident grid size from occupancy (host-side query; not in the timed graph)
    int maxB = 0;
    if (hipOccupancyMaxActiveBlocksPerMultiprocessor(&maxB, (const void*)k_mega,
                                                     256, 0) != hipSuccess || maxB < 1)
        maxB = 2;   // conservative fallback (40 KB LDS guarantees >= 2)
    long long gridLL = (long long)maxB * 256;
    if (gridLL > 2048) gridLL = 2048;
    int grid = (int)gridLL;

    const unsigned long long* ei64 = (const unsigned long long*)ei;
    float* outp = (float*)d_out;
    void* args[] = {
        (void*)&ei64, (void*)&E, (void*)&n, (void*)&nscan,
        (void*)&flag, (void*)&hist, (void*)&tmp, (void*)&partial,
        (void*)&row_ptr, (void*)&cursor, (void*)&colv,
        (void*)&x, (void*)&b_gcn,
        (void*)&W_gat, (void*)&att_s, (void*)&att_d,
        (void*)&W_p, (void*)&W_gcn,
        (void*)&b_p, (void*)&b_gat,
        (void*)&gamma, (void*)&beta,
        (void*)&Wt_post, (void*)&Wt_xw,
        (void*)&w_s, (void*)&w_d, (void*)&dinv,
        (void*)&xws, (void*)&h1b,
        (void*)&a_sv, (void*)&a_dv,
        (void*)&X, (void*)&outp
    };
    hipLaunchCooperativeKernel((const void*)k_mega, dim3(grid), dim3(256),
                               args, 0, stream);
}